// Round 1
// baseline (1285.971 us; speedup 1.0000x reference)
//
#include <hip/hip_runtime.h>
#include <stdint.h>

// ---------------------------------------------------------------------------
// ResidueGraphModel: aanet_proj (512->1024->1024->512->80, ReLU) -> in_net
// (80->512) -> GIN sum-aggregation + MLP (512->512->512) -> out_net (512->80).
// All GEMMs in bf16 MFMA (fp32 accumulate), m97-style 128x128 tile structure.
// Outputs fp32: d_out = [peptide_mask (N*80) | peptide_feat (N*80)].
// ---------------------------------------------------------------------------

using bf16x8 = __attribute__((ext_vector_type(8))) short;
using f32x4  = __attribute__((ext_vector_type(4))) float;

__device__ inline unsigned short f2bf(float f) {
    union { float f; unsigned u; } v; v.f = f;
    unsigned u = v.u;
    u += 0x7FFFu + ((u >> 16) & 1u);   // RNE
    return (unsigned short)(u >> 16);
}
__device__ inline float bf2f(unsigned short u) {
    return __uint_as_float(((unsigned)u) << 16);
}

// ---------------- weight transpose+convert: W[K][M] f32 -> Wt[Mp][Kp] bf16 --
__global__ void rg_transpose_w(const float* __restrict__ W, unsigned short* __restrict__ Wt,
                               int K, int M, int Kp, int Mp) {
    __shared__ float t[32][33];
    int mb = blockIdx.x * 32, kb = blockIdx.y * 32;
    int tx = threadIdx.x, ty = threadIdx.y;
    int k = kb + ty, m = mb + tx;
    float v = (k < K && m < M) ? W[(size_t)k * M + m] : 0.f;
    t[ty][tx] = v;
    __syncthreads();
    int mo = mb + ty, ko = kb + tx;
    if (mo < Mp && ko < Kp) Wt[(size_t)mo * Kp + ko] = f2bf(t[tx][ty]);
}

// ---------------- f32 -> bf16 elementwise (4 per thread) --------------------
__global__ void rg_f32_to_bf16(const float* __restrict__ in, unsigned short* __restrict__ out, int n) {
    int i = (blockIdx.x * 256 + threadIdx.x) * 4;
    if (i + 3 < n) {
        float4 v = *(const float4*)(in + i);
        ushort4 o; o.x = f2bf(v.x); o.y = f2bf(v.y); o.z = f2bf(v.z); o.w = f2bf(v.w);
        *(ushort4*)(out + i) = o;
    }
}

// ---------------- GEMM: C[N,Mp] = act(A[N,Kp] @ Wt[Mp,Kp]^T + bias) ---------
// bf16 A/Wt, fp32 accum. 128x128 tile, BK=64, 4 waves of 4x4 16x16x32 MFMAs.
template <bool RELU, bool OUT_BF, bool OUT_F32>
__global__ __launch_bounds__(256) void rg_gemm_bt(
    const unsigned short* __restrict__ A, const unsigned short* __restrict__ Bt,
    const float* __restrict__ bias, int Mvalid,
    unsigned short* __restrict__ outB, float* __restrict__ outF,
    int Nrows, int Kp, int Mp)
{
    __shared__ __align__(16) unsigned short As[128 * 64];
    __shared__ __align__(16) unsigned short Bs[128 * 64];
    const int tid  = threadIdx.x;
    const int lane = tid & 63;
    const int w    = tid >> 6;
    const int wm   = w & 1, wn = w >> 1;
    const int rowBase = blockIdx.x * 128;
    const int nBase   = blockIdx.y * 128;

    f32x4 acc[4][4];
#pragma unroll
    for (int i = 0; i < 4; ++i)
#pragma unroll
        for (int j = 0; j < 4; ++j) acc[i][j] = (f32x4){0.f, 0.f, 0.f, 0.f};

    const int nkt = Kp >> 6;
    for (int kt = 0; kt < nkt; ++kt) {
        __syncthreads();
        const int k0 = kt * 64;
#pragma unroll
        for (int i = 0; i < 4; ++i) {
            int c  = i * 256 + tid;
            int r  = c >> 3;            // tile row
            int cc = (c & 7) * 8;       // col elem offset
            int gr = rowBase + r; if (gr >= Nrows) gr = Nrows - 1;
            const unsigned short* gp = A + (size_t)gr * Kp + k0 + cc;
            __builtin_amdgcn_global_load_lds(
                (const __attribute__((address_space(1))) void*)gp,
                (__attribute__((address_space(3))) void*)(&As[c * 8]), 16, 0, 0);
        }
#pragma unroll
        for (int i = 0; i < 4; ++i) {
            int c  = i * 256 + tid;
            int r  = c >> 3;
            int cc = (c & 7) * 8;
            const unsigned short* gp = Bt + (size_t)(nBase + r) * Kp + k0 + cc;
            __builtin_amdgcn_global_load_lds(
                (const __attribute__((address_space(1))) void*)gp,
                (__attribute__((address_space(3))) void*)(&Bs[c * 8]), 16, 0, 0);
        }
        __syncthreads();
#pragma unroll
        for (int kk = 0; kk < 2; ++kk) {
            bf16x8 a[4], b[4];
#pragma unroll
            for (int i = 0; i < 4; ++i)
                a[i] = *(const bf16x8*)&As[(wm * 64 + i * 16 + (lane & 15)) * 64 + kk * 32 + (lane >> 4) * 8];
#pragma unroll
            for (int j = 0; j < 4; ++j)
                b[j] = *(const bf16x8*)&Bs[(wn * 64 + j * 16 + (lane & 15)) * 64 + kk * 32 + (lane >> 4) * 8];
#pragma unroll
            for (int i = 0; i < 4; ++i)
#pragma unroll
                for (int j = 0; j < 4; ++j)
                    acc[i][j] = __builtin_amdgcn_mfma_f32_16x16x32_bf16(a[i], b[j], acc[i][j], 0, 0, 0);
        }
    }

    // epilogue: C/D layout col=lane&15, row=(lane>>4)*4+reg  [verified m89/m91]
    const int colq = lane & 15;
    const int rowq = (lane >> 4) * 4;
#pragma unroll
    for (int j = 0; j < 4; ++j) {
        int col = nBase + wn * 64 + j * 16 + colq;
        float bv = (col < Mvalid) ? bias[col] : 0.f;
#pragma unroll
        for (int i = 0; i < 4; ++i) {
            int row0 = rowBase + wm * 64 + i * 16 + rowq;
#pragma unroll
            for (int r = 0; r < 4; ++r) {
                int row = row0 + r;
                if (row < Nrows) {
                    float v = acc[i][j][r] + bv;
                    if (RELU) v = v > 0.f ? v : 0.f;
                    if (OUT_BF)  outB[(size_t)row * Mp + col] = f2bf(v);
                    if (OUT_F32) { if (col < Mvalid) outF[(size_t)row * Mvalid + col] = v; }
                }
            }
        }
    }
}

// ---------------- CSR build ------------------------------------------------
__global__ void rg_count_edges(const int* __restrict__ ei, int E, int* __restrict__ cnt) {
    int e = blockIdx.x * 256 + threadIdx.x;
    if (e < E) atomicAdd(&cnt[ei[E + e]], 1);
}

__global__ void rg_scan(const int* __restrict__ cnt, int* __restrict__ rowptr,
                        int* __restrict__ cursor, int Nn) {
    __shared__ int sdata[1024];
    __shared__ int stotal;
    int tid = threadIdx.x;
    if (tid == 0) stotal = 0;
    __syncthreads();
    for (int base = 0; base < Nn; base += 1024) {
        int i = base + tid;
        int v = (i < Nn) ? cnt[i] : 0;
        sdata[tid] = v;
        __syncthreads();
        for (int off = 1; off < 1024; off <<= 1) {
            int t = (tid >= off) ? sdata[tid - off] : 0;
            __syncthreads();
            sdata[tid] += t;
            __syncthreads();
        }
        int incl = sdata[tid];
        int tot = stotal;
        if (i < Nn) { int ex = tot + incl - v; rowptr[i] = ex; cursor[i] = ex; }
        __syncthreads();
        if (tid == 1023) stotal = tot + incl;
        __syncthreads();
    }
    if (tid == 0) rowptr[Nn] = stotal;
}

__global__ void rg_scatter_edges(const int* __restrict__ ei, int E,
                                 int* __restrict__ cursor, int* __restrict__ cols) {
    int e = blockIdx.x * 256 + threadIdx.x;
    if (e < E) {
        int d = ei[E + e];
        int p = atomicAdd(&cursor[d], 1);
        cols[p] = ei[e];
    }
}

// ---------------- GIN aggregation: g[i] = x[i] + sum_{src->i} x[src] --------
__global__ __launch_bounds__(128) void rg_gin_agg(
    const unsigned short* __restrict__ x, const int* __restrict__ rowptr,
    const int* __restrict__ cols, unsigned short* __restrict__ g, int Nn)
{
    int node = blockIdx.x;
    int tid = threadIdx.x;                  // 128 threads x 4 cols = 512
    size_t off = (size_t)node * 512 + tid * 4;
    ushort4 s = *(const ushort4*)(x + off);
    float a0 = bf2f(s.x), a1 = bf2f(s.y), a2 = bf2f(s.z), a3 = bf2f(s.w);
    int beg = rowptr[node], end = rowptr[node + 1];
    for (int e = beg; e < end; ++e) {
        int src = cols[e];
        ushort4 v = *(const ushort4*)(x + (size_t)src * 512 + tid * 4);
        a0 += bf2f(v.x); a1 += bf2f(v.y); a2 += bf2f(v.z); a3 += bf2f(v.w);
    }
    ushort4 o; o.x = f2bf(a0); o.y = f2bf(a1); o.z = f2bf(a2); o.w = f2bf(a3);
    *(ushort4*)(g + off) = o;
}

// ---------------------------------------------------------------------------
extern "C" void kernel_launch(void* const* d_in, const int* in_sizes, int n_in,
                              void* d_out, int out_size, void* d_ws, size_t ws_size,
                              hipStream_t stream)
{
    const float* feat = (const float*)d_in[0];
    const int*   ei   = (const int*)d_in[1];
    const float* W1 = (const float*)d_in[2];  const float* b1 = (const float*)d_in[3];
    const float* W2 = (const float*)d_in[4];  const float* b2 = (const float*)d_in[5];
    const float* W3 = (const float*)d_in[6];  const float* b3 = (const float*)d_in[7];
    const float* W4 = (const float*)d_in[8];  const float* b4 = (const float*)d_in[9];
    const float* Wi = (const float*)d_in[10]; const float* bi = (const float*)d_in[11];
    const float* Wg1 = (const float*)d_in[12]; const float* bg1 = (const float*)d_in[13];
    const float* Wg2 = (const float*)d_in[14]; const float* bg2 = (const float*)d_in[15];
    const float* Wo = (const float*)d_in[16]; const float* bo = (const float*)d_in[17];

    const int N = in_sizes[0] / 512;   // 50000
    const int E = in_sizes[1] / 2;     // 800000

    // workspace layout (~266 MB total)
    char* ws = (char*)d_ws;
    size_t o = 0;
    auto alloc = [&](size_t bytes) { char* p = ws + o; o += (bytes + 255) & ~(size_t)255; return p; };
    unsigned short* bufA = (unsigned short*)alloc((size_t)N * 1024 * 2); // h1 / pf_bf16 / g / g2
    unsigned short* bufB = (unsigned short*)alloc((size_t)N * 1024 * 2); // h2 / x
    unsigned short* bufC = (unsigned short*)alloc((size_t)N * 512 * 2);  // A0 / h3 / r1
    unsigned short* W1t = (unsigned short*)alloc((size_t)1024 * 512 * 2);
    unsigned short* W2t = (unsigned short*)alloc((size_t)1024 * 1024 * 2);
    unsigned short* W3t = (unsigned short*)alloc((size_t)512 * 1024 * 2);
    unsigned short* W4t = (unsigned short*)alloc((size_t)128 * 512 * 2);
    unsigned short* Wit = (unsigned short*)alloc((size_t)512 * 128 * 2);
    unsigned short* Wg1t = (unsigned short*)alloc((size_t)512 * 512 * 2);
    unsigned short* Wg2t = (unsigned short*)alloc((size_t)512 * 512 * 2);
    unsigned short* Wot = (unsigned short*)alloc((size_t)128 * 512 * 2);
    int* cnt    = (int*)alloc((size_t)N * 4);
    int* rowptr = (int*)alloc((size_t)(N + 1) * 4);
    int* cursor = (int*)alloc((size_t)N * 4);
    int* cols   = (int*)alloc((size_t)E * 4);

    float* out_mask = (float*)d_out;                 // [N,80]
    float* out_feat = (float*)d_out + (size_t)N * 80; // [N,80]

    dim3 tb(32, 32);
    // grid = (Mp/32, Kp/32)
    rg_transpose_w<<<dim3(32, 16), tb, 0, stream>>>(W1, W1t, 512, 1024, 512, 1024);
    rg_transpose_w<<<dim3(32, 32), tb, 0, stream>>>(W2, W2t, 1024, 1024, 1024, 1024);
    rg_transpose_w<<<dim3(16, 32), tb, 0, stream>>>(W3, W3t, 1024, 512, 1024, 512);
    rg_transpose_w<<<dim3(4, 16), tb, 0, stream>>>(W4, W4t, 512, 80, 512, 128);
    rg_transpose_w<<<dim3(16, 4), tb, 0, stream>>>(Wi, Wit, 80, 512, 128, 512);
    rg_transpose_w<<<dim3(16, 16), tb, 0, stream>>>(Wg1, Wg1t, 512, 512, 512, 512);
    rg_transpose_w<<<dim3(16, 16), tb, 0, stream>>>(Wg2, Wg2t, 512, 512, 512, 512);
    rg_transpose_w<<<dim3(4, 16), tb, 0, stream>>>(Wo, Wot, 512, 80, 512, 128);

    rg_f32_to_bf16<<<(N * 512) / 1024, 256, 0, stream>>>(feat, bufC, N * 512);

    const int gN = (N + 127) / 128; // 391
    // L1: h1 = relu(A0 @ W1 + b1)   [N,1024]
    rg_gemm_bt<true, true, false><<<dim3(gN, 8), 256, 0, stream>>>(bufC, W1t, b1, 1024, bufA, nullptr, N, 512, 1024);
    // L2: h2 = relu(h1 @ W2 + b2)   [N,1024]
    rg_gemm_bt<true, true, false><<<dim3(gN, 8), 256, 0, stream>>>(bufA, W2t, b2, 1024, bufB, nullptr, N, 1024, 1024);
    // L3: h3 = relu(h2 @ W3 + b3)   [N,512]
    rg_gemm_bt<true, true, false><<<dim3(gN, 4), 256, 0, stream>>>(bufB, W3t, b3, 512, bufC, nullptr, N, 1024, 512);
    // L4: pf = h3 @ W4 + b4  -> fp32 out_feat + bf16 padded [N,128]
    rg_gemm_bt<false, true, true><<<dim3(gN, 1), 256, 0, stream>>>(bufC, W4t, b4, 80, bufA, out_feat, N, 512, 128);
    // L5: x = pf @ Win + bin  [N,512]  (K padded 80->128)
    rg_gemm_bt<false, true, false><<<dim3(gN, 4), 256, 0, stream>>>(bufA, Wit, bi, 512, bufB, nullptr, N, 128, 512);

    // CSR build + aggregation: g = x + segment_sum(x[src], dst)
    hipMemsetAsync(cnt, 0, (size_t)N * 4, stream);
    rg_count_edges<<<(E + 255) / 256, 256, 0, stream>>>(ei, E, cnt);
    rg_scan<<<1, 1024, 0, stream>>>(cnt, rowptr, cursor, N);
    rg_scatter_edges<<<(E + 255) / 256, 256, 0, stream>>>(ei, E, cursor, cols);
    rg_gin_agg<<<N, 128, 0, stream>>>(bufB, rowptr, cols, bufA, N);

    // L6: r1 = relu(g @ Wg1 + bg1)  [N,512]
    rg_gemm_bt<true, true, false><<<dim3(gN, 4), 256, 0, stream>>>(bufA, Wg1t, bg1, 512, bufC, nullptr, N, 512, 512);
    // L7: g2 = r1 @ Wg2 + bg2       [N,512]
    rg_gemm_bt<false, true, false><<<dim3(gN, 4), 256, 0, stream>>>(bufC, Wg2t, bg2, 512, bufA, nullptr, N, 512, 512);
    // L8: mask = g2 @ Wout + bout -> fp32 out_mask
    rg_gemm_bt<false, false, true><<<dim3(gN, 1), 256, 0, stream>>>(bufA, Wot, bo, 80, nullptr, out_mask, N, 512, 128);
}

// Round 2
// 874.209 us; speedup vs baseline: 1.4710x; 1.4710x over previous
//
#include <hip/hip_runtime.h>
#include <stdint.h>

// ---------------------------------------------------------------------------
// ResidueGraphModel: aanet_proj (512->1024->1024->512->80, ReLU) -> in_net
// (80->512) -> GIN sum-aggregation + MLP (512->512->512) -> out_net (512->80).
// bf16 MFMA GEMMs (fp32 accumulate), 128x128 tiles, BK=64.
// R2 changes: XOR-swizzled LDS staging (kills 16-way bank conflicts),
// operand-swapped MFMA (cols in regs -> 8B packed C stores), XCD-grouped
// block decode (A-strip L2 reuse across column passes), aggregation moved
// before in_net (80-dim gather, deg-scaled bias in L5), hierarchical scan.
// Outputs fp32: d_out = [peptide_mask (N*80) | peptide_feat (N*80)].
// ---------------------------------------------------------------------------

using bf16x8 = __attribute__((ext_vector_type(8))) short;
using f32x4  = __attribute__((ext_vector_type(4))) float;

__device__ inline unsigned short f2bf(float f) {
    union { float f; unsigned u; } v; v.f = f;
    unsigned u = v.u;
    u += 0x7FFFu + ((u >> 16) & 1u);   // RNE
    return (unsigned short)(u >> 16);
}
__device__ inline float bf2f(unsigned u16) {
    return __uint_as_float(u16 << 16);
}

// ---------------- weight transpose+convert: W[K][M] f32 -> Wt[Mp][Kp] bf16 --
__global__ void rg_transpose_w(const float* __restrict__ W, unsigned short* __restrict__ Wt,
                               int K, int M, int Kp, int Mp) {
    __shared__ float t[32][33];
    int mb = blockIdx.x * 32, kb = blockIdx.y * 32;
    int tx = threadIdx.x, ty = threadIdx.y;
    int k = kb + ty, m = mb + tx;
    float v = (k < K && m < M) ? W[(size_t)k * M + m] : 0.f;
    t[ty][tx] = v;
    __syncthreads();
    int mo = mb + ty, ko = kb + tx;
    if (mo < Mp && ko < Kp) Wt[(size_t)mo * Kp + ko] = f2bf(t[tx][ty]);
}

// ---------------- f32 -> bf16 elementwise (4 per thread) --------------------
__global__ void rg_f32_to_bf16(const float* __restrict__ in, unsigned short* __restrict__ out, int n) {
    int i = (blockIdx.x * 256 + threadIdx.x) * 4;
    if (i + 3 < n) {
        float4 v = *(const float4*)(in + i);
        ushort4 o; o.x = f2bf(v.x); o.y = f2bf(v.y); o.z = f2bf(v.z); o.w = f2bf(v.w);
        *(ushort4*)(out + i) = o;
    }
}

// ---------------- GEMM: C[N,Mp] = act(A[N,Kp] @ Wt[Mp,Kp]^T + bscale*bias) --
// XOR swizzle: LDS chunk q (16B) of a tile row r holds global chunk
// (q&7)^(r&7); staging lane loads the matching global address, fragment
// reads apply the same XOR -> 2-way (free) bank aliasing instead of 16-way.
// Operand swap: weights as first MFMA operand -> acc regs hold 4 consecutive
// output columns -> 8B packed stores.
template <bool RELU, bool OUT_BF, bool OUT_F32, bool DEGB>
__global__ __launch_bounds__(256) void rg_gemm(
    const unsigned short* __restrict__ A, const unsigned short* __restrict__ Bt,
    const float* __restrict__ bias, const int* __restrict__ deg, int Mvalid,
    unsigned short* __restrict__ outB, float* __restrict__ outF,
    int Nrows, int Kp, int Mp, int gN, int MT)
{
    __shared__ __align__(16) unsigned short As[128 * 64];
    __shared__ __align__(16) unsigned short Bs[128 * 64];

    // XCD-grouped decode: same row strip's MT col-blocks -> same (bid&7) class,
    // 8 apart in issue order (L2 reuse if XCD=id%8; L3 temporal reuse anyway).
    int bid = blockIdx.x;
    int xcd = bid & 7;
    int slot = bid >> 3;
    int c = slot % MT;
    int rsub = slot / MT;
    int rt = rsub * 8 + xcd;
    if (rt >= gN) return;
    const int rowBase = rt * 128;
    const int nBase   = c * 128;

    const int tid  = threadIdx.x;
    const int lane = tid & 63;
    const int w    = tid >> 6;
    const int wm   = w & 1, wn = w >> 1;

    f32x4 acc[4][4];
#pragma unroll
    for (int i = 0; i < 4; ++i)
#pragma unroll
        for (int j = 0; j < 4; ++j) acc[i][j] = (f32x4){0.f, 0.f, 0.f, 0.f};

    const int nkt = Kp >> 6;
    for (int kt = 0; kt < nkt; ++kt) {
        __syncthreads();
        const int k0 = kt * 64;
#pragma unroll
        for (int i = 0; i < 4; ++i) {
            int q   = i * 256 + tid;       // LDS chunk index (fixed: base+lane*16)
            int r   = q >> 3;
            int cbg = (q & 7) ^ (r & 7);   // global chunk this LDS slot receives
            int gr  = rowBase + r; if (gr >= Nrows) gr = Nrows - 1;
            const unsigned short* gp = A + (size_t)gr * Kp + k0 + cbg * 8;
            __builtin_amdgcn_global_load_lds(
                (const __attribute__((address_space(1))) void*)gp,
                (__attribute__((address_space(3))) void*)(&As[q * 8]), 16, 0, 0);
        }
#pragma unroll
        for (int i = 0; i < 4; ++i) {
            int q   = i * 256 + tid;
            int r   = q >> 3;
            int cbg = (q & 7) ^ (r & 7);
            const unsigned short* gp = Bt + (size_t)(nBase + r) * Kp + k0 + cbg * 8;
            __builtin_amdgcn_global_load_lds(
                (const __attribute__((address_space(1))) void*)gp,
                (__attribute__((address_space(3))) void*)(&Bs[q * 8]), 16, 0, 0);
        }
        __syncthreads();
#pragma unroll
        for (int kk = 0; kk < 2; ++kk) {
            bf16x8 a[4], b[4];
            const int cb = kk * 4 + (lane >> 4);
#pragma unroll
            for (int i = 0; i < 4; ++i) {
                int r = wm * 64 + i * 16 + (lane & 15);
                a[i] = *(const bf16x8*)&As[(r * 8 + (cb ^ (r & 7))) * 8];
            }
#pragma unroll
            for (int j = 0; j < 4; ++j) {
                int r = wn * 64 + j * 16 + (lane & 15);
                b[j] = *(const bf16x8*)&Bs[(r * 8 + (cb ^ (r & 7))) * 8];
            }
#pragma unroll
            for (int i = 0; i < 4; ++i)
#pragma unroll
                for (int j = 0; j < 4; ++j)
                    // swapped: weights first -> D[m_op=col][n_op=row]
                    acc[i][j] = __builtin_amdgcn_mfma_f32_16x16x32_bf16(b[j], a[i], acc[i][j], 0, 0, 0);
        }
    }

    // epilogue (swapped layout): row = ...+(lane&15); col = ...+quad*4+reg
    const int quad = lane >> 4;
#pragma unroll
    for (int i = 0; i < 4; ++i) {
        int row = rowBase + wm * 64 + i * 16 + (lane & 15);
        if (row >= Nrows) continue;
        float sc = 1.f;
        if (DEGB) sc = 1.f + (float)deg[row];
#pragma unroll
        for (int j = 0; j < 4; ++j) {
            int colb = nBase + wn * 64 + j * 16 + quad * 4;
            float4 bv = (colb < Mvalid) ? *(const float4*)(bias + colb)
                                        : (float4){0.f, 0.f, 0.f, 0.f};
            float v0 = acc[i][j][0] + sc * bv.x;
            float v1 = acc[i][j][1] + sc * bv.y;
            float v2 = acc[i][j][2] + sc * bv.z;
            float v3 = acc[i][j][3] + sc * bv.w;
            if (RELU) {
                v0 = v0 > 0.f ? v0 : 0.f; v1 = v1 > 0.f ? v1 : 0.f;
                v2 = v2 > 0.f ? v2 : 0.f; v3 = v3 > 0.f ? v3 : 0.f;
            }
            if (OUT_BF) {
                ushort4 o; o.x = f2bf(v0); o.y = f2bf(v1); o.z = f2bf(v2); o.w = f2bf(v3);
                *(ushort4*)(outB + (size_t)row * Mp + colb) = o;
            }
            if (OUT_F32) {
                if (colb < Mvalid)
                    *(float4*)(outF + (size_t)row * Mvalid + colb) = (float4){v0, v1, v2, v3};
            }
        }
    }
}

// ---------------- CSR build ------------------------------------------------
__global__ void rg_count_edges(const int* __restrict__ ei, int E, int* __restrict__ cnt) {
    int e = blockIdx.x * 256 + threadIdx.x;
    if (e < E) atomicAdd(&cnt[ei[E + e]], 1);
}

__global__ void rg_scan_block(const int* __restrict__ cnt, int* __restrict__ scanned,
                              int* __restrict__ bsums, int Nn) {
    __shared__ int sd[1024];
    int tid = threadIdx.x;
    int i = blockIdx.x * 1024 + tid;
    int v = (i < Nn) ? cnt[i] : 0;
    sd[tid] = v;
    __syncthreads();
    for (int off = 1; off < 1024; off <<= 1) {
        int t = (tid >= off) ? sd[tid - off] : 0;
        __syncthreads();
        sd[tid] += t;
        __syncthreads();
    }
    if (i < Nn) scanned[i] = sd[tid];
    if (tid == 1023) bsums[blockIdx.x] = sd[1023];
}

__global__ void rg_scan_sums(int* __restrict__ b, int nb) {
    if (threadIdx.x == 0) {
        int acc = 0;
        for (int i = 0; i < nb; ++i) { int t = b[i]; b[i] = acc; acc += t; }
    }
}

__global__ void rg_scan_add(const int* __restrict__ scanned, const int* __restrict__ bsums,
                            const int* __restrict__ cnt, int* __restrict__ rowptr,
                            int* __restrict__ cursor, int Nn, int E) {
    int i = blockIdx.x * 1024 + threadIdx.x;
    if (i < Nn) {
        int ex = scanned[i] - cnt[i] + bsums[blockIdx.x];
        rowptr[i] = ex; cursor[i] = ex;
    }
    if (i == 0) rowptr[Nn] = E;
}

__global__ void rg_scatter_edges(const int* __restrict__ ei, int E,
                                 int* __restrict__ cursor, int* __restrict__ cols) {
    int e = blockIdx.x * 256 + threadIdx.x;
    if (e < E) {
        int d = ei[E + e];
        int p = atomicAdd(&cursor[d], 1);
        cols[p] = ei[e];
    }
}

// ---------------- 80-dim aggregation: s[i] = pf[i] + sum_{src->i} pf[src] --
// pf is [N,128] bf16 (padded). One wave per node, 2 cols/lane (4B loads).
__global__ __launch_bounds__(256) void rg_agg80(
    const unsigned short* __restrict__ pf, const int* __restrict__ rowptr,
    const int* __restrict__ cols, unsigned short* __restrict__ s, int Nn)
{
    int node = blockIdx.x * 4 + (threadIdx.x >> 6);
    if (node >= Nn) return;
    int lane = threadIdx.x & 63;
    const unsigned* xp = (const unsigned*)pf;   // 64 uints per row
    size_t off = (size_t)node * 64 + lane;
    unsigned u = xp[off];
    float a0 = bf2f(u & 0xffffu), a1 = bf2f(u >> 16);
    int beg = rowptr[node], end = rowptr[node + 1];
    for (int e = beg; e < end; ++e) {
        int src = cols[e];
        unsigned v = xp[(size_t)src * 64 + lane];
        a0 += bf2f(v & 0xffffu); a1 += bf2f(v >> 16);
    }
    unsigned o = (unsigned)f2bf(a0) | ((unsigned)f2bf(a1) << 16);
    ((unsigned*)s)[off] = o;
}

// ---------------------------------------------------------------------------
extern "C" void kernel_launch(void* const* d_in, const int* in_sizes, int n_in,
                              void* d_out, int out_size, void* d_ws, size_t ws_size,
                              hipStream_t stream)
{
    const float* feat = (const float*)d_in[0];
    const int*   ei   = (const int*)d_in[1];
    const float* W1 = (const float*)d_in[2];  const float* b1 = (const float*)d_in[3];
    const float* W2 = (const float*)d_in[4];  const float* b2 = (const float*)d_in[5];
    const float* W3 = (const float*)d_in[6];  const float* b3 = (const float*)d_in[7];
    const float* W4 = (const float*)d_in[8];  const float* b4 = (const float*)d_in[9];
    const float* Wi = (const float*)d_in[10]; const float* bi = (const float*)d_in[11];
    const float* Wg1 = (const float*)d_in[12]; const float* bg1 = (const float*)d_in[13];
    const float* Wg2 = (const float*)d_in[14]; const float* bg2 = (const float*)d_in[15];
    const float* Wo = (const float*)d_in[16]; const float* bo = (const float*)d_in[17];

    const int N = in_sizes[0] / 512;   // 50000
    const int E = in_sizes[1] / 2;     // 800000

    char* ws = (char*)d_ws;
    size_t o = 0;
    auto alloc = [&](size_t bytes) { char* p = ws + o; o += (bytes + 255) & ~(size_t)255; return p; };
    unsigned short* bufA = (unsigned short*)alloc((size_t)N * 1024 * 2); // h1 / pf / g / ...
    unsigned short* bufB = (unsigned short*)alloc((size_t)N * 1024 * 2); // h2 / r1
    unsigned short* bufC = (unsigned short*)alloc((size_t)N * 512 * 2);  // A0 / h3 / s / g2
    unsigned short* W1t = (unsigned short*)alloc((size_t)1024 * 512 * 2);
    unsigned short* W2t = (unsigned short*)alloc((size_t)1024 * 1024 * 2);
    unsigned short* W3t = (unsigned short*)alloc((size_t)512 * 1024 * 2);
    unsigned short* W4t = (unsigned short*)alloc((size_t)128 * 512 * 2);
    unsigned short* Wit = (unsigned short*)alloc((size_t)512 * 128 * 2);
    unsigned short* Wg1t = (unsigned short*)alloc((size_t)512 * 512 * 2);
    unsigned short* Wg2t = (unsigned short*)alloc((size_t)512 * 512 * 2);
    unsigned short* Wot = (unsigned short*)alloc((size_t)128 * 512 * 2);
    int* cnt    = (int*)alloc((size_t)N * 4);
    int* rowptr = (int*)alloc((size_t)(N + 1) * 4);
    int* cursor = (int*)alloc((size_t)N * 4);
    int* cols   = (int*)alloc((size_t)E * 4);   // also reused as `scanned` before scatter
    int* bsums  = (int*)alloc(256);

    float* out_mask = (float*)d_out;                  // [N,80]
    float* out_feat = (float*)d_out + (size_t)N * 80; // [N,80]

    // ---- CSR build (independent of GEMM chain) ----
    int* scanned = cols;  // overlay: consumed by rg_scan_add before rg_scatter writes cols
    hipMemsetAsync(cnt, 0, (size_t)N * 4, stream);
    rg_count_edges<<<(E + 255) / 256, 256, 0, stream>>>(ei, E, cnt);
    const int nb = (N + 1023) / 1024;
    rg_scan_block<<<nb, 1024, 0, stream>>>(cnt, scanned, bsums, N);
    rg_scan_sums<<<1, 64, 0, stream>>>(bsums, nb);
    rg_scan_add<<<nb, 1024, 0, stream>>>(scanned, bsums, cnt, rowptr, cursor, N, E);
    rg_scatter_edges<<<(E + 255) / 256, 256, 0, stream>>>(ei, E, cursor, cols);

    // ---- weight prep ----
    dim3 tb(32, 32);
    rg_transpose_w<<<dim3(32, 16), tb, 0, stream>>>(W1, W1t, 512, 1024, 512, 1024);
    rg_transpose_w<<<dim3(32, 32), tb, 0, stream>>>(W2, W2t, 1024, 1024, 1024, 1024);
    rg_transpose_w<<<dim3(16, 32), tb, 0, stream>>>(W3, W3t, 1024, 512, 1024, 512);
    rg_transpose_w<<<dim3(4, 16), tb, 0, stream>>>(W4, W4t, 512, 80, 512, 128);
    rg_transpose_w<<<dim3(16, 4), tb, 0, stream>>>(Wi, Wit, 80, 512, 128, 512);
    rg_transpose_w<<<dim3(16, 16), tb, 0, stream>>>(Wg1, Wg1t, 512, 512, 512, 512);
    rg_transpose_w<<<dim3(16, 16), tb, 0, stream>>>(Wg2, Wg2t, 512, 512, 512, 512);
    rg_transpose_w<<<dim3(4, 16), tb, 0, stream>>>(Wo, Wot, 512, 80, 512, 128);

    rg_f32_to_bf16<<<(N * 512) / 1024, 256, 0, stream>>>(feat, bufC, N * 512);

    const int gN = (N + 127) / 128;          // 391
    const int rg8 = ((gN + 7) / 8) * 8;      // 392
    auto grid = [&](int MT) { return dim3(rg8 * MT); };

    // L1: h1 = relu(A0 @ W1 + b1)   [N,1024]
    rg_gemm<true, true, false, false><<<grid(8), 256, 0, stream>>>(bufC, W1t, b1, nullptr, 1024, bufA, nullptr, N, 512, 1024, gN, 8);
    // L2: h2 = relu(h1 @ W2 + b2)   [N,1024]
    rg_gemm<true, true, false, false><<<grid(8), 256, 0, stream>>>(bufA, W2t, b2, nullptr, 1024, bufB, nullptr, N, 1024, 1024, gN, 8);
    // L3: h3 = relu(h2 @ W3 + b3)   [N,512]
    rg_gemm<true, true, false, false><<<grid(4), 256, 0, stream>>>(bufB, W3t, b3, nullptr, 512, bufC, nullptr, N, 1024, 512, gN, 4);
    // L4: pf = h3 @ W4 + b4  -> fp32 out_feat + bf16 padded [N,128]
    rg_gemm<false, true, true, false><<<grid(1), 256, 0, stream>>>(bufC, W4t, b4, nullptr, 80, bufA, out_feat, N, 512, 128, gN, 1);

    // 80-dim aggregation: s = pf + segsum(pf[src]) -> bufC[:, :128]
    rg_agg80<<<(N + 3) / 4, 256, 0, stream>>>(bufA, rowptr, cols, bufC, N);

    // L5: g = s @ Win + (1+deg)*bin  [N,512]   (agg moved before affine in_net)
    rg_gemm<false, true, false, true><<<grid(4), 256, 0, stream>>>(bufC, Wit, bi, cnt, 512, bufA, nullptr, N, 128, 512, gN, 4);
    // L6: r1 = relu(g @ Wg1 + bg1)  [N,512]
    rg_gemm<true, true, false, false><<<grid(4), 256, 0, stream>>>(bufA, Wg1t, bg1, nullptr, 512, bufB, nullptr, N, 512, 512, gN, 4);
    // L7: g2 = r1 @ Wg2 + bg2       [N,512]
    rg_gemm<false, true, false, false><<<grid(4), 256, 0, stream>>>(bufB, Wg2t, bg2, nullptr, 512, bufC, nullptr, N, 512, 512, gN, 4);
    // L8: mask = g2 @ Wout + bout -> fp32 out_mask
    rg_gemm<false, false, true, false><<<grid(1), 256, 0, stream>>>(bufC, Wot, bo, nullptr, 80, nullptr, out_mask, N, 512, 128, gN, 1);
}